// Round 1
// baseline (811.588 us; speedup 1.0000x reference)
//
#include <hip/hip_runtime.h>

// ---------------------------------------------------------------------------
// MAF (nflows MaskedAutoregressiveFlow) forward log-prob, fully fused.
// D=45, H=256, NB=6, L=2, K=8, M=23, tails='linear', TAIL=-log(1e-6).
//
// Structure:
//   prep_*  : mask + bf16-cast weights into d_ws (runs every call; ws is
//             re-poisoned by the harness before each timed launch).
//   maf_main: one WG = 64 batch rows; entire 6-block pipeline in LDS.
//             GEMMs via v_mfma_f32_16x16x32_bf16 (A/B frag: [m|n=lane&15]
//             [k=(lane>>4)*8+j], C/D: col=lane&15,row=(lane>>4)*4+reg).
// ---------------------------------------------------------------------------

typedef __bf16 bf16;
typedef __bf16 bf16x8 __attribute__((ext_vector_type(8)));
typedef float  f32x4  __attribute__((ext_vector_type(4)));
typedef unsigned int u32x4 __attribute__((ext_vector_type(4)));

#define TAILF  13.815510557964274f      /* -log(1e-6) */
#define LOGZ   41.352233994210265f      /* 0.5*45*log(2*pi) */

// ---------------- workspace layout (bytes) ----------------
// W0m  bf16 [6][256][64]        @ 0        (196608)
// Whm  bf16 [6][2][256][256]    @ 196608   (1572864)
// Wfm  bf16 [6][5][256][256]    @ 1769472  (3932160)  (packed, 11 feats/group)
// beff f32  [6][256]            @ 5701632  (6144)     (b0+bc)
// bfp  f32  [6][5][256]         @ 5707776  (30720)    (packed bf)
// Wcc  f32  [6][256]            @ 5738496  (6144)
#define WS_W0M   0
#define WS_WHM   196608
#define WS_WFM   1769472
#define WS_BEFF  5701632
#define WS_BFP   5707776
#define WS_WCC   5738496
#define WS_NEED  5744640

// ---------------- prep kernels ----------------

__global__ void prep_w0(const float* __restrict__ W0, const float* __restrict__ b0,
                        const float* __restrict__ Wc, const float* __restrict__ bc,
                        bf16* __restrict__ W0m, float* __restrict__ beff,
                        float* __restrict__ Wcc)
{
    int idx = blockIdx.x * 256 + threadIdx.x;          // 6*256*64 = 98304
    if (idx >= 6 * 256 * 64) return;
    int i = idx & 63;
    int j = (idx >> 6) & 255;
    int b = idx >> 14;
    float v = 0.f;
    if (i < 45 && (j % 44) >= i)                       // m0: deg_h[j] >= i+1
        v = W0[(b * 256 + j) * 45 + i];
    W0m[idx] = (bf16)v;
    if (i == 0) {
        beff[b * 256 + j] = b0[b * 256 + j] + bc[b * 256 + j];
        Wcc[b * 256 + j]  = Wc[b * 256 + j];
    }
}

__global__ void prep_wh(const float* __restrict__ Wh, bf16* __restrict__ Whm)
{
    int idx = blockIdx.x * 256 + threadIdx.x;          // 6*2*256*256 = 786432
    if (idx >= 6 * 2 * 256 * 256) return;
    int k = idx & 255;
    int j = (idx >> 8) & 255;
    float v = ((j % 44) >= (k % 44)) ? Wh[idx] : 0.f;  // mh: deg_h[j] >= deg_h[k]
    Whm[idx] = (bf16)v;
}

__global__ void prep_wf(const float* __restrict__ Wf, const float* __restrict__ bfv,
                        bf16* __restrict__ Wfm, float* __restrict__ bfp)
{
    int idx = blockIdx.x * 256 + threadIdx.x;          // 6*5*256*256 = 1966080
    if (idx >= 6 * 5 * 256 * 256) return;
    int k  = idx & 255;
    int p  = (idx >> 8) & 255;
    int bg = idx >> 16;                                // b*5+g, 0..29
    int g  = bg % 5, b = bg / 5;
    int f  = 11 * g + p / 23;                          // global feature
    int m  = p % 23;
    bool valid = (p < 253) && (f < 45);
    float v = 0.f;
    if (valid && (f > (k % 44)))                       // mf strict: f+1 > deg_h[k]
        v = Wf[(b * 1035 + f * 23 + m) * 256 + k];
    Wfm[idx] = (bf16)v;
    if (k == 0)
        bfp[bg * 256 + p] = valid ? bfv[b * 1035 + f * 23 + m] : 0.f;
}

// ---------------- fused main kernel ----------------
// LDS offsets (total 130560 B, dynamic):
#define SO_ZF    0        /* float [64][48]  12288 */
#define SO_ZB    12288    /* bf16  [64][72]   9216 */
#define SO_HIDA  21504    /* bf16  [64][264] 33792 */
#define SO_HIDB  55296    /* bf16  [64][264] 33792 (also params buffer) */
#define SO_WPAN  89088    /* bf16  [2][256][40] 40960 (k-panel dbuf, +8 pad) */
#define SO_COND  130048   /* float [64] */
#define SO_LD    130304   /* float [64] */
#define SMEM_BYTES 130560

// One GEMM layer: out[64 rows][NCOL cols] = A[64][K] * Wg[NCOL][K]^T (+epilogue)
// MODE 0: + beff[col] + cond[row]*Wc[col]          -> dst (hidA)
// MODE 1: + bh[col], relu                          -> dst (hidA, in-place safe)
// MODE 2: + bfp[col]                               -> dst (hidB = params)
template<int KT, int NCOL, int MODE>
__device__ __forceinline__ void gemm_layer(
    const bf16* Asrc, int lda,
    const bf16* __restrict__ Wg, int ldk,
    const float* __restrict__ bias, const float* __restrict__ wcol,
    const float* condl, bf16* dst, bf16* wpan,
    int t, int w, int l15, int q)
{
    constexpr int JPW = (NCOL == 256) ? 4 : 1;         // j-tiles per wave
    const bool active  = (NCOL == 256) || (w * 16 < NCOL);
    const int  colbase = (NCOL == 256) ? (w * 64) : (w * 16);

    f32x4 acc[4][JPW] = {};
    const int j0 = t >> 2;                             // 0..63 (panel row)
    const int kg = t & 3;                              // 16B chunk within 32-k

    // stage panel kt=0 (global -> LDS, bf16, padded stride 40)
    #pragma unroll
    for (int c = 0; c < 4; ++c) {
        int j = j0 + c * 64;
        if (j < NCOL) {
            u32x4 v = *reinterpret_cast<const u32x4*>(Wg + (size_t)j * ldk + kg * 8);
            *reinterpret_cast<u32x4*>(wpan + j * 40 + kg * 8) = v;
        }
    }
    __syncthreads();

    #pragma unroll
    for (int kt = 0; kt < KT; ++kt) {
        u32x4 nx[4];
        if (kt + 1 < KT) {                             // prefetch next panel
            #pragma unroll
            for (int c = 0; c < 4; ++c) {
                int j = j0 + c * 64;
                if (j < NCOL)
                    nx[c] = *reinterpret_cast<const u32x4*>(
                        Wg + (size_t)j * ldk + (kt + 1) * 32 + kg * 8);
            }
        }
        if (active) {
            bf16x8 af[4];
            #pragma unroll
            for (int rt = 0; rt < 4; ++rt)
                af[rt] = *reinterpret_cast<const bf16x8*>(
                    Asrc + (rt * 16 + l15) * lda + kt * 32 + q * 8);
            const bf16* cur = wpan + (kt & 1) * 10240;
            #pragma unroll
            for (int jt = 0; jt < JPW; ++jt) {
                bf16x8 bfr = *reinterpret_cast<const bf16x8*>(
                    cur + (colbase + jt * 16 + l15) * 40 + q * 8);
                #pragma unroll
                for (int rt = 0; rt < 4; ++rt)
                    acc[rt][jt] = __builtin_amdgcn_mfma_f32_16x16x32_bf16(
                        af[rt], bfr, acc[rt][jt], 0, 0, 0);
            }
        }
        if (kt + 1 < KT) {
            bf16* nxt = wpan + ((kt + 1) & 1) * 10240;
            #pragma unroll
            for (int c = 0; c < 4; ++c) {
                int j = j0 + c * 64;
                if (j < NCOL)
                    *reinterpret_cast<u32x4*>(nxt + j * 40 + kg * 8) = nx[c];
            }
        }
        __syncthreads();
    }

    // epilogue (all A-frag reads are behind the last barrier -> in-place OK)
    if (active) {
        #pragma unroll
        for (int jt = 0; jt < JPW; ++jt) {
            int col = colbase + jt * 16 + l15;
            float bv  = bias[col];
            float wcv = (MODE == 0) ? wcol[col] : 0.f;
            #pragma unroll
            for (int rt = 0; rt < 4; ++rt) {
                #pragma unroll
                for (int v = 0; v < 4; ++v) {
                    int row = rt * 16 + q * 4 + v;     // C/D: row=(lane>>4)*4+v
                    float val = acc[rt][jt][v] + bv;
                    if (MODE == 0) val += condl[row] * wcv;
                    if (MODE == 1) val = fmaxf(val, 0.f);
                    dst[row * 264 + col] = (bf16)val;
                }
            }
        }
    }
    __syncthreads();
}

// Rational-quadratic spline for NF features starting at fb (params in pbuf,
// group-local cols fl*23..fl*23+22, bf16). Updates zf/zb/ldl.
template<int NF>
__device__ __forceinline__ void do_spline(int fb, float* zf, bf16* zb,
                                          const bf16* pbuf, float* ldl, int t)
{
    for (int task = t; task < 64 * NF; task += 256) {
        int r  = task / NF;
        int fl = task - r * NF;
        const bf16* pp = pbuf + r * 264 + fl * 23;
        float P[23];
        #pragma unroll
        for (int m = 0; m < 23; ++m) P[m] = (float)pp[m];

        float xin = zf[r * 48 + fb + fl];
        float xc  = fminf(fmaxf(xin, -TAILF), TAILF);
        bool inside = (xin >= -TAILF) && (xin <= TAILF);

        // widths: softmax(P[0..7]/16) -> min_bw + 0.992*softmax
        float mw = P[0];
        #pragma unroll
        for (int i = 1; i < 8; ++i) mw = fmaxf(mw, P[i]);
        float ew[8], sw = 0.f;
        #pragma unroll
        for (int i = 0; i < 8; ++i) { ew[i] = __expf((P[i] - mw) * 0.0625f); sw += ew[i]; }
        float rws = 0.992f / sw;
        float cw[9]; cw[0] = -TAILF;
        #pragma unroll
        for (int i = 0; i < 8; ++i)
            cw[i + 1] = cw[i] + 2.f * TAILF * (1e-3f + ew[i] * rws);
        cw[8] = TAILF;
        float wb[8];
        #pragma unroll
        for (int i = 0; i < 8; ++i) wb[i] = cw[i + 1] - cw[i];

        // heights: softmax(P[8..15]/16)
        float mh = P[8];
        #pragma unroll
        for (int i = 1; i < 8; ++i) mh = fmaxf(mh, P[8 + i]);
        float eh[8], sh = 0.f;
        #pragma unroll
        for (int i = 0; i < 8; ++i) { eh[i] = __expf((P[8 + i] - mh) * 0.0625f); sh += eh[i]; }
        float rhs = 0.992f / sh;
        float ch[9]; ch[0] = -TAILF;
        #pragma unroll
        for (int i = 0; i < 8; ++i)
            ch[i + 1] = ch[i] + 2.f * TAILF * (1e-3f + eh[i] * rhs);
        ch[8] = TAILF;
        float hb[8];
        #pragma unroll
        for (int i = 0; i < 8; ++i) hb[i] = ch[i + 1] - ch[i];

        // derivatives: d[0]=d[8]=1 (pad const), d[i]=1e-3+softplus(P[15+i])
        float dd[9];
        dd[0] = 1.0f; dd[8] = 1.0f;
        #pragma unroll
        for (int i = 1; i < 8; ++i)
            dd[i] = 1e-3f + __logf(1.f + __expf(P[15 + i]));

        // bin select (unrolled scan keeps everything compile-time indexed)
        float icw = cw[0], ich = ch[0], ibw = wb[0], ibh = hb[0];
        float id0 = dd[0], id1 = dd[1];
        #pragma unroll
        for (int i = 1; i < 8; ++i) {
            bool ge = xc >= cw[i];
            icw = ge ? cw[i] : icw;  ich = ge ? ch[i] : ich;
            ibw = ge ? wb[i] : ibw;  ibh = ge ? hb[i] : ibh;
            id0 = ge ? dd[i] : id0;  id1 = ge ? dd[i + 1] : id1;
        }

        float th  = (xc - icw) / ibw;
        float th1 = th * (1.f - th);
        float dl  = ibh / ibw;
        float den = dl + (id0 + id1 - 2.f * dl) * th1;
        float yy  = ich + ibh * (dl * th * th + id0 * th1) / den;
        float num = dl * dl * (id1 * th * th + 2.f * dl * th1
                               + id0 * (1.f - th) * (1.f - th));
        float lad = __logf(num) - 2.f * __logf(den);

        if (inside) {
            zf[r * 48 + fb + fl] = yy;
            zb[r * 72 + fb + fl] = (bf16)yy;
            atomicAdd(&ldl[r], lad);
        }
    }
}

__global__ __launch_bounds__(256, 1) void maf_main(
    const float* __restrict__ x, const float* __restrict__ cond,
    const float* __restrict__ bh_all,
    const bf16* __restrict__ W0m, const bf16* __restrict__ Whm,
    const bf16* __restrict__ Wfm,
    const float* __restrict__ beff, const float* __restrict__ bfp,
    const float* __restrict__ Wcc,
    float* __restrict__ out, int B)
{
    extern __shared__ char smem[];
    float* zf    = (float*)(smem + SO_ZF);
    bf16*  zb    = (bf16*)(smem + SO_ZB);
    bf16*  hidA  = (bf16*)(smem + SO_HIDA);
    bf16*  hidB  = (bf16*)(smem + SO_HIDB);
    bf16*  wpan  = (bf16*)(smem + SO_WPAN);
    float* condl = (float*)(smem + SO_COND);
    float* ldl   = (float*)(smem + SO_LD);

    const int t   = threadIdx.x;
    const int r0  = blockIdx.x * 64;
    const int w   = t >> 6;
    const int lane = t & 63;
    const int l15 = lane & 15;
    const int q   = lane >> 4;

    // init: zero zb pad cols 45..71, load x -> zf + zb, cond, ld (disjoint)
    for (int i = t; i < 64 * 27; i += 256) {
        int r = i / 27, c = i - (i / 27) * 27;
        zb[r * 72 + 45 + c] = (bf16)0.f;
    }
    for (int i = t; i < 64 * 45; i += 256) {
        int r = i / 45, f = i - (i / 45) * 45;
        float v = (r0 + r < B) ? x[(size_t)(r0 + r) * 45 + f] : 0.f;
        zf[r * 48 + f] = v;
        zb[r * 72 + f] = (bf16)v;
    }
    if (t < 64) {
        condl[t] = (r0 + t < B) ? cond[r0 + t] : 0.f;
        ldl[t]   = 0.f;
    }
    __syncthreads();

    #pragma unroll 1
    for (int b = 0; b < 6; ++b) {
        // input MADE layer (K=64 padded from 45), + cond*Wc + (b0+bc), no relu
        gemm_layer<2, 256, 0>(zb, 72, W0m + b * 16384, 64,
                              beff + b * 256, Wcc + b * 256, condl,
                              hidA, wpan, t, w, l15, q);
        // 2 hidden layers, relu, in-place
        #pragma unroll 1
        for (int l = 0; l < 2; ++l)
            gemm_layer<8, 256, 1>(hidA, 264, Whm + (b * 2 + l) * 65536, 256,
                                  bh_all + (b * 2 + l) * 256, nullptr, condl,
                                  hidA, wpan, t, w, l15, q);
        // params (5 packed groups) + spline
        #pragma unroll 1
        for (int g = 0; g < 4; ++g) {
            gemm_layer<8, 256, 2>(hidA, 264, Wfm + (b * 5 + g) * 65536, 256,
                                  bfp + (b * 5 + g) * 256, nullptr, condl,
                                  hidB, wpan, t, w, l15, q);
            do_spline<11>(g * 11, zf, zb, hidB, ldl, t);
            __syncthreads();
        }
        gemm_layer<8, 32, 2>(hidA, 264, Wfm + (b * 5 + 4) * 65536, 256,
                             bfp + (b * 5 + 4) * 256, nullptr, condl,
                             hidB, wpan, t, w, l15, q);
        do_spline<1>(44, zf, zb, hidB, ldl, t);
        __syncthreads();
    }

    if (t < 64 && r0 + t < B) {
        float s = 0.f;
        #pragma unroll
        for (int f = 0; f < 45; ++f) { float v = zf[t * 48 + f]; s += v * v; }
        out[r0 + t] = -0.5f * s - LOGZ + ldl[t];
    }
}

// ---------------- host entry ----------------

extern "C" void kernel_launch(void* const* d_in, const int* in_sizes, int n_in,
                              void* d_out, int out_size, void* d_ws, size_t ws_size,
                              hipStream_t stream)
{
    const float* x    = (const float*)d_in[0];
    const float* cond = (const float*)d_in[1];
    const float* W0   = (const float*)d_in[2];
    const float* b0   = (const float*)d_in[3];
    const float* Wc   = (const float*)d_in[4];
    const float* bc   = (const float*)d_in[5];
    const float* Wh   = (const float*)d_in[6];
    const float* bh   = (const float*)d_in[7];
    const float* Wf   = (const float*)d_in[8];
    const float* bfv  = (const float*)d_in[9];
    float* out = (float*)d_out;

    const int B = in_sizes[0] / 45;
    if (ws_size < (size_t)WS_NEED) return;   // fail loudly (poisoned output)

    char* ws = (char*)d_ws;
    bf16*  W0m  = (bf16*)(ws + WS_W0M);
    bf16*  Whm  = (bf16*)(ws + WS_WHM);
    bf16*  Wfm  = (bf16*)(ws + WS_WFM);
    float* beff = (float*)(ws + WS_BEFF);
    float* bfp  = (float*)(ws + WS_BFP);
    float* Wcc  = (float*)(ws + WS_WCC);

    prep_w0<<<384, 256, 0, stream>>>(W0, b0, Wc, bc, W0m, beff, Wcc);
    prep_wh<<<3072, 256, 0, stream>>>(Wh, Whm);
    prep_wf<<<7680, 256, 0, stream>>>(Wf, bfv, Wfm, bfp);

    static int smem_set = 0;
    (void)hipFuncSetAttribute((const void*)maf_main,
                              hipFuncAttributeMaxDynamicSharedMemorySize,
                              SMEM_BYTES);
    (void)smem_set;

    const int nwg = (B + 63) / 64;
    maf_main<<<nwg, 256, SMEM_BYTES, stream>>>(
        x, cond, bh, W0m, Whm, Wfm, beff, bfp, Wcc, out, B);
}

// Round 2
// 695.211 us; speedup vs baseline: 1.1674x; 1.1674x over previous
//
#include <hip/hip_runtime.h>

// ---------------------------------------------------------------------------
// MAF forward log-prob, fully fused. D=45, H=256, NB=6, L=2, K=8, M=23.
// R2: 32x32x16 bf16 MFMA, direct global->VGPR B loads (no LDS weight panel,
// no per-kt barriers), 512 thr/WG, 80 KiB LDS -> 2 blocks/CU (4 waves/SIMD).
// Params regrouped as 5 groups x 9 features (207 cols, padded to 224).
// ---------------------------------------------------------------------------

typedef __bf16 bf16;
typedef __bf16 bf16x8 __attribute__((ext_vector_type(8)));
typedef float  f32x16 __attribute__((ext_vector_type(16)));

#define TAILF  13.815510557964274f      /* -log(1e-6) */
#define LOGZ   41.352233994210265f      /* 0.5*45*log(2*pi) */

// ---------------- workspace layout (bytes) ----------------
#define WS_W0M   0            /* bf16 [6][256][64]     196608 */
#define WS_WHM   196608       /* bf16 [6][2][256][256] 1572864 */
#define WS_WFM   1769472      /* bf16 [6][5][224][256] 3440640 */
#define WS_BEFF  5210112      /* f32  [6][256]         6144 */
#define WS_BFP   5216256      /* f32  [6][5][224]      26880 */
#define WS_WCC   5243136      /* f32  [6][256]         6144 */
#define WS_NEED  5249280

#define N_W0  (6*256*64)        /* 98304  */
#define N_WH  (6*2*256*256)     /* 786432 */
#define N_WF  (6*5*224*256)     /* 1720320 */
#define N_PREP (N_W0 + N_WH + N_WF)

// ---------------- merged prep kernel ----------------
__global__ void prep_all(const float* __restrict__ W0, const float* __restrict__ b0,
                         const float* __restrict__ Wc, const float* __restrict__ bc,
                         const float* __restrict__ Wh, const float* __restrict__ Wf,
                         const float* __restrict__ bfv,
                         bf16* __restrict__ W0m, bf16* __restrict__ Whm,
                         bf16* __restrict__ Wfm,
                         float* __restrict__ beff, float* __restrict__ bfp,
                         float* __restrict__ Wcc)
{
    int idx = blockIdx.x * 256 + threadIdx.x;
    if (idx < N_W0) {
        // W0m [b][j=256][i=64], mask m0: deg_h[j] >= i+1
        int i = idx & 63, j = (idx >> 6) & 255, b = idx >> 14;
        float v = 0.f;
        if (i < 45 && (j % 44) >= i)
            v = W0[(b * 256 + j) * 45 + i];
        W0m[idx] = (bf16)v;
        if (i == 0) {
            beff[b * 256 + j] = b0[b * 256 + j] + bc[b * 256 + j];
            Wcc[b * 256 + j]  = Wc[b * 256 + j];
        }
    } else if (idx < N_W0 + N_WH) {
        // Whm [b][l][j=256][k=256], mask mh: deg_h[j] >= deg_h[k]
        int id = idx - N_W0;
        int k = id & 255, j = (id >> 8) & 255;
        float v = ((j % 44) >= (k % 44)) ? Wh[id] : 0.f;
        Whm[id] = (bf16)v;
    } else if (idx < N_PREP) {
        // Wfm [b][g][c=224][k=256]; c<207: f=9g+c/23, m=c%23; strict mask f>deg_h[k]
        int id = idx - (N_W0 + N_WH);
        int k  = id & 255;
        int bg = id >> 8;
        int c  = bg % 224;  bg /= 224;        // bg = b*5+g
        int b  = bg / 5, g = bg - 5 * (bg / 5);
        int f  = 9 * g + c / 23;
        int m  = c - (c / 23) * 23;
        bool valid = (c < 207);
        float v = 0.f;
        if (valid && (f > (k % 44)))
            v = Wf[(b * 1035 + f * 23 + m) * 256 + k];
        Wfm[id] = (bf16)v;
        if (k == 0)
            bfp[bg * 224 + c] = valid ? bfv[b * 1035 + f * 23 + m] : 0.f;
    }
}

// ---------------- fused main kernel ----------------
// LDS (dynamic, 81920 B total = 80 KiB -> 2 blocks/CU):
#define SO_ZF    0        /* float [64][46]   11776 */
#define SO_ZB    11776    /* bf16  [64][72]    9216 */
#define SO_HIDA  20992    /* bf16  [64][264]  33792 */
#define SO_PBUF  54784    /* bf16  [64][208]  26624 */
#define SO_COND  81408    /* float [64] */
#define SO_LD    81664    /* float [64] */
#define SMEM_BYTES 81920

// GEMM layer via 32x32x16 bf16 MFMA. 8 waves = 2 row-groups x 4 col-groups;
// each wave: 1 row-tile (32 rows) x 2 col-tiles (64 cols). B-frags stream
// straight from global (Wg row-major [NCOL][K]); A-frags ds_read_b128.
// A/B frag: [idx=lane&31][k=(lane>>5)*8+j]. C/D: col=lane&31,
// row=(reg&3)+8*(reg>>2)+4*(lane>>5).
// MODE 0: +bias[col]+cond[row]*wcol[col]; MODE 1: +bias, relu; MODE 2: +bias.
template<int KT, int NJT, int MODE, int LIMIT>
__device__ __forceinline__ void gemm32(
    const bf16* Asrc, int lda,
    const bf16* __restrict__ Wg, int K,
    const float* __restrict__ bias, const float* __restrict__ wcol,
    const float* condl, bf16* dst, int ldd,
    int w, int lane, bool preEpiSync)
{
    const int cg  = w & 3;
    const int rg  = w >> 2;
    const int l31 = lane & 31;
    const int k8  = (lane >> 5) * 8;
    const bool act1 = (NJT == 8) || (cg < 3);   // jt1 live?

    const bf16* Ap  = Asrc + (rg * 32 + l31) * lda + k8;
    const bf16* Bp0 = Wg + (size_t)(cg * 64 + l31) * K + k8;
    const bf16* Bp1 = Bp0 + 32 * (size_t)K;

    f32x16 acc0 = {};
    f32x16 acc1 = {};
    #pragma unroll
    for (int kt = 0; kt < KT; ++kt) {
        bf16x8 a  = *reinterpret_cast<const bf16x8*>(Ap + kt * 16);
        bf16x8 b0 = *reinterpret_cast<const bf16x8*>(Bp0 + kt * 16);
        acc0 = __builtin_amdgcn_mfma_f32_32x32x16_bf16(a, b0, acc0, 0, 0, 0);
        if (act1) {
            bf16x8 b1 = *reinterpret_cast<const bf16x8*>(Bp1 + kt * 16);
            acc1 = __builtin_amdgcn_mfma_f32_32x32x16_bf16(a, b1, acc1, 0, 0, 0);
        }
    }

    if (preEpiSync) __syncthreads();   // in-place layers: all A reads done

    const int col0 = cg * 64 + l31;
    const float bv0  = bias[col0];
    const float bv1  = act1 ? bias[col0 + 32] : 0.f;
    const float wcv0 = (MODE == 0) ? wcol[col0] : 0.f;
    const float wcv1 = (MODE == 0 && act1) ? wcol[col0 + 32] : 0.f;
    #pragma unroll
    for (int r = 0; r < 16; ++r) {
        int row = rg * 32 + (r & 3) + 8 * (r >> 2) + 4 * (lane >> 5);
        float v0 = acc0[r] + bv0;
        if (MODE == 0) v0 += condl[row] * wcv0;
        if (MODE == 1) v0 = fmaxf(v0, 0.f);
        if (NJT == 8 || col0 < LIMIT) dst[row * ldd + col0] = (bf16)v0;
        if (act1) {
            float v1 = acc1[r] + bv1;
            if (MODE == 0) v1 += condl[row] * wcv1;
            if (MODE == 1) v1 = fmaxf(v1, 0.f);
            if (NJT == 8 || col0 + 32 < LIMIT) dst[row * ldd + col0 + 32] = (bf16)v1;
        }
    }
    __syncthreads();
}

// RQ spline for NF features starting at fb; params in pbuf (stride 208,
// group-local col fl*23..+22). Updates zf/zb/ldl.
template<int NF>
__device__ __forceinline__ void do_spline(int fb, float* zf, bf16* zb,
                                          const bf16* pbuf, float* ldl, int t)
{
    for (int task = t; task < 64 * NF; task += 512) {
        int r  = task / NF;
        int fl = task - r * NF;
        const bf16* pp = pbuf + r * 208 + fl * 23;
        float P[23];
        #pragma unroll
        for (int m = 0; m < 23; ++m) P[m] = (float)pp[m];

        float xin = zf[r * 46 + fb + fl];
        float xc  = fminf(fmaxf(xin, -TAILF), TAILF);
        bool inside = (xin >= -TAILF) && (xin <= TAILF);

        float mw = P[0];
        #pragma unroll
        for (int i = 1; i < 8; ++i) mw = fmaxf(mw, P[i]);
        float ew[8], sw = 0.f;
        #pragma unroll
        for (int i = 0; i < 8; ++i) { ew[i] = __expf((P[i] - mw) * 0.0625f); sw += ew[i]; }
        float rws = 0.992f / sw;
        float cw[9]; cw[0] = -TAILF;
        #pragma unroll
        for (int i = 0; i < 8; ++i)
            cw[i + 1] = cw[i] + 2.f * TAILF * (1e-3f + ew[i] * rws);
        cw[8] = TAILF;
        float wb[8];
        #pragma unroll
        for (int i = 0; i < 8; ++i) wb[i] = cw[i + 1] - cw[i];

        float mh = P[8];
        #pragma unroll
        for (int i = 1; i < 8; ++i) mh = fmaxf(mh, P[8 + i]);
        float eh[8], sh = 0.f;
        #pragma unroll
        for (int i = 0; i < 8; ++i) { eh[i] = __expf((P[8 + i] - mh) * 0.0625f); sh += eh[i]; }
        float rhs = 0.992f / sh;
        float ch[9]; ch[0] = -TAILF;
        #pragma unroll
        for (int i = 0; i < 8; ++i)
            ch[i + 1] = ch[i] + 2.f * TAILF * (1e-3f + eh[i] * rhs);
        ch[8] = TAILF;
        float hb[8];
        #pragma unroll
        for (int i = 0; i < 8; ++i) hb[i] = ch[i + 1] - ch[i];

        float dd[9];
        dd[0] = 1.0f; dd[8] = 1.0f;
        #pragma unroll
        for (int i = 1; i < 8; ++i)
            dd[i] = 1e-3f + __logf(1.f + __expf(P[15 + i]));

        float icw = cw[0], ich = ch[0], ibw = wb[0], ibh = hb[0];
        float id0 = dd[0], id1 = dd[1];
        #pragma unroll
        for (int i = 1; i < 8; ++i) {
            bool ge = xc >= cw[i];
            icw = ge ? cw[i] : icw;  ich = ge ? ch[i] : ich;
            ibw = ge ? wb[i] : ibw;  ibh = ge ? hb[i] : ibh;
            id0 = ge ? dd[i] : id0;  id1 = ge ? dd[i + 1] : id1;
        }

        float th  = (xc - icw) / ibw;
        float th1 = th * (1.f - th);
        float dl  = ibh / ibw;
        float den = dl + (id0 + id1 - 2.f * dl) * th1;
        float yy  = ich + ibh * (dl * th * th + id0 * th1) / den;
        float num = dl * dl * (id1 * th * th + 2.f * dl * th1
                               + id0 * (1.f - th) * (1.f - th));
        float lad = __logf(num) - 2.f * __logf(den);

        if (inside) {
            zf[r * 46 + fb + fl] = yy;
            zb[r * 72 + fb + fl] = (bf16)yy;
            atomicAdd(&ldl[r], lad);
        }
    }
}

__global__ __launch_bounds__(512, 4) void maf_main(
    const float* __restrict__ x, const float* __restrict__ cond,
    const float* __restrict__ bh_all,
    const bf16* __restrict__ W0m, const bf16* __restrict__ Whm,
    const bf16* __restrict__ Wfm,
    const float* __restrict__ beff, const float* __restrict__ bfp,
    const float* __restrict__ Wcc,
    float* __restrict__ out, int B)
{
    extern __shared__ char smem[];
    float* zf    = (float*)(smem + SO_ZF);
    bf16*  zb    = (bf16*)(smem + SO_ZB);
    bf16*  hidA  = (bf16*)(smem + SO_HIDA);
    bf16*  pbuf  = (bf16*)(smem + SO_PBUF);
    float* condl = (float*)(smem + SO_COND);
    float* ldl   = (float*)(smem + SO_LD);

    const int t    = threadIdx.x;
    const int r0   = blockIdx.x * 64;
    const int w    = t >> 6;
    const int lane = t & 63;

    // init: zb pad cols 45..71 zero, x -> zf+zb, cond, ld
    for (int i = t; i < 64 * 27; i += 512) {
        int r = i / 27, c = i - (i / 27) * 27;
        zb[r * 72 + 45 + c] = (bf16)0.f;
    }
    for (int i = t; i < 64 * 45; i += 512) {
        int r = i / 45, f = i - (i / 45) * 45;
        float v = (r0 + r < B) ? x[(size_t)(r0 + r) * 45 + f] : 0.f;
        zf[r * 46 + f] = v;
        zb[r * 72 + f] = (bf16)v;
    }
    if (t < 64) {
        condl[t] = (r0 + t < B) ? cond[r0 + t] : 0.f;
        ldl[t]   = 0.f;
    }
    __syncthreads();

    #pragma unroll 1
    for (int b = 0; b < 6; ++b) {
        // input MADE layer: K=64 (padded from 45), +cond*Wc + (b0+bc)
        gemm32<4, 8, 0, 256>(zb, 72, W0m + b * 16384, 64,
                             beff + b * 256, Wcc + b * 256, condl,
                             hidA, 264, w, lane, false);
        // 2 hidden layers, relu, in-place (pre-epilogue sync required)
        #pragma unroll 1
        for (int l = 0; l < 2; ++l)
            gemm32<16, 8, 1, 256>(hidA, 264, Whm + (b * 2 + l) * 65536, 256,
                                  bh_all + (b * 2 + l) * 256, nullptr, condl,
                                  hidA, 264, w, lane, true);
        // params: 5 groups x 9 features (207 cols, NJT=7, mask col<208)
        #pragma unroll 1
        for (int g = 0; g < 5; ++g) {
            gemm32<16, 7, 2, 208>(hidA, 264, Wfm + (size_t)(b * 5 + g) * 57344, 256,
                                  bfp + (b * 5 + g) * 224, nullptr, condl,
                                  pbuf, 208, w, lane, false);
            do_spline<9>(g * 9, zf, zb, pbuf, ldl, t);
            __syncthreads();
        }
    }

    if (t < 64 && r0 + t < B) {
        float s = 0.f;
        #pragma unroll
        for (int f = 0; f < 45; ++f) { float v = zf[t * 46 + f]; s += v * v; }
        out[r0 + t] = -0.5f * s - LOGZ + ldl[t];
    }
}

// ---------------- host entry ----------------
extern "C" void kernel_launch(void* const* d_in, const int* in_sizes, int n_in,
                              void* d_out, int out_size, void* d_ws, size_t ws_size,
                              hipStream_t stream)
{
    const float* x    = (const float*)d_in[0];
    const float* cond = (const float*)d_in[1];
    const float* W0   = (const float*)d_in[2];
    const float* b0   = (const float*)d_in[3];
    const float* Wc   = (const float*)d_in[4];
    const float* bc   = (const float*)d_in[5];
    const float* Wh   = (const float*)d_in[6];
    const float* bh   = (const float*)d_in[7];
    const float* Wf   = (const float*)d_in[8];
    const float* bfv  = (const float*)d_in[9];
    float* out = (float*)d_out;

    const int B = in_sizes[0] / 45;
    if (ws_size < (size_t)WS_NEED) return;   // fail loudly

    char* ws = (char*)d_ws;
    bf16*  W0m  = (bf16*)(ws + WS_W0M);
    bf16*  Whm  = (bf16*)(ws + WS_WHM);
    bf16*  Wfm  = (bf16*)(ws + WS_WFM);
    float* beff = (float*)(ws + WS_BEFF);
    float* bfp  = (float*)(ws + WS_BFP);
    float* Wcc  = (float*)(ws + WS_WCC);

    prep_all<<<(N_PREP + 255) / 256, 256, 0, stream>>>(
        W0, b0, Wc, bc, Wh, Wf, bfv, W0m, Whm, Wfm, beff, bfp, Wcc);

    (void)hipFuncSetAttribute((const void*)maf_main,
                              hipFuncAttributeMaxDynamicSharedMemorySize,
                              SMEM_BYTES);

    const int nwg = (B + 63) / 64;
    maf_main<<<nwg, 512, SMEM_BYTES, stream>>>(
        x, cond, bh, W0m, Whm, Wfm, beff, bfp, Wcc, out, B);
}

// Round 3
// 375.001 us; speedup vs baseline: 2.1642x; 1.8539x over previous
//
#include <hip/hip_runtime.h>

// ---------------------------------------------------------------------------
// MAF forward log-prob, fully fused. D=45, H=256, NB=6, L=2, K=8, M=23.
// R3: weights pre-swizzled into MFMA-fragment-coalesced chunks (1KB per
// [col-group][kt]: lane*16B contiguous). Waves re-tiled 8 col-groups x 1
// row-group (64 rows x 32 cols each, 2 acc) so each weight is read exactly
// once per WG with fully-coalesced global loads. 512 thr/WG, 80 KiB LDS,
// 2 WGs/CU.
// ---------------------------------------------------------------------------

typedef __bf16 bf16;
typedef __bf16 bf16x8 __attribute__((ext_vector_type(8)));
typedef float  f32x16 __attribute__((ext_vector_type(16)));

#define TAILF  13.815510557964274f      /* -log(1e-6) */
#define LOGZ   41.352233994210265f      /* 0.5*45*log(2*pi) */

// ---------------- workspace layout (bytes) ----------------
// All weight buffers hold packed fragment chunks: chunk c = (cg,kt), 512 bf16,
// element (lane,j) = W[col = cg*32 + (lane&31)][k = kt*16 + (lane>>5)*8 + j].
#define WS_W0M   0            /* bf16 [6][8 cg][4 kt][512]   196608 */
#define WS_WHM   196608       /* bf16 [12][8 cg][16 kt][512] 1572864 */
#define WS_WFM   1769472      /* bf16 [30][7 cg][16 kt][512] 3440640 */
#define WS_BEFF  5210112      /* f32  [6][256]   6144 */
#define WS_BFP   5216256      /* f32  [30][224]  26880 */
#define WS_WCC   5243136      /* f32  [6][256]   6144 */
#define WS_NEED  5249280

#define N_W0  (6*256*64)        /* 98304   */
#define N_WH  (6*2*256*256)     /* 786432  */
#define N_WF  (6*5*224*256)     /* 1720320 */
#define N_PREP (N_W0 + N_WH + N_WF)

// ---------------- merged prep kernel (mask + cast + fragment-pack) ---------
__global__ void prep_all(const float* __restrict__ W0, const float* __restrict__ b0,
                         const float* __restrict__ Wc, const float* __restrict__ bc,
                         const float* __restrict__ Wh, const float* __restrict__ Wf,
                         const float* __restrict__ bfv,
                         bf16* __restrict__ W0m, bf16* __restrict__ Whm,
                         bf16* __restrict__ Wfm,
                         float* __restrict__ beff, float* __restrict__ bfp,
                         float* __restrict__ Wcc)
{
    int idx = blockIdx.x * 256 + threadIdx.x;
    if (idx < N_W0) {
        // W0 packed: chunk = idx>>9; kt=chunk&3, cg=(chunk>>2)&7, b=chunk>>5
        int j = idx & 7, lane = (idx >> 3) & 63, chunk = idx >> 9;
        int kt = chunk & 3, cg = (chunk >> 2) & 7, b = chunk >> 5;
        int col = cg * 32 + (lane & 31);
        int k   = kt * 16 + (lane >> 5) * 8 + j;
        float v = 0.f;
        if (k < 45 && (col % 44) >= k)                 // m0: deg_h[col] >= k+1
            v = W0[(b * 256 + col) * 45 + k];
        W0m[idx] = (bf16)v;
        if (k == 0) {
            beff[b * 256 + col] = b0[b * 256 + col] + bc[b * 256 + col];
            Wcc[b * 256 + col]  = Wc[b * 256 + col];
        }
    } else if (idx < N_W0 + N_WH) {
        int id = idx - N_W0;
        int j = id & 7, lane = (id >> 3) & 63, chunk = id >> 9;
        int kt = chunk & 15, cg = (chunk >> 4) & 7, bl = chunk >> 7;  // bl=b*2+l
        int col = cg * 32 + (lane & 31);
        int k   = kt * 16 + (lane >> 5) * 8 + j;
        float v = ((col % 44) >= (k % 44)) ? Wh[bl * 65536 + col * 256 + k] : 0.f;
        Whm[id] = (bf16)v;
    } else if (idx < N_PREP) {
        int id = idx - (N_W0 + N_WH);
        int j = id & 7, lane = (id >> 3) & 63, chunk = id >> 9;
        int kt = chunk & 15, t2 = chunk >> 4;
        int cg = t2 % 7, bg = t2 / 7;                  // bg = b*5+g
        int b  = bg / 5, g = bg - 5 * b;
        int col = cg * 32 + (lane & 31);               // 0..223
        int k   = kt * 16 + (lane >> 5) * 8 + j;
        int f   = 9 * g + col / 23;
        int m   = col - (col / 23) * 23;
        bool valid = (col < 207);
        float v = 0.f;
        if (valid && (f > (k % 44)))                   // mf strict
            v = Wf[(b * 1035 + f * 23 + m) * 256 + k];
        Wfm[id] = (bf16)v;
        if (k == 0)
            bfp[bg * 224 + col] = valid ? bfv[b * 1035 + f * 23 + m] : 0.f;
    }
}

// ---------------- fused main kernel ----------------
// LDS (dynamic, 81920 B = 80 KiB -> 2 blocks/CU):
#define SO_ZF    0        /* float [64][46]   11776 */
#define SO_ZB    11776    /* bf16  [64][72]    9216 */
#define SO_HIDA  20992    /* bf16  [64][264]  33792 */
#define SO_PBUF  54784    /* bf16  [64][208]  26624 */
#define SO_COND  81408    /* float [64] */
#define SO_LD    81664    /* float [64] */
#define SMEM_BYTES 81920

// GEMM: out[64 rows][NACT*32 cols] += A[64][KT*16] * W^T. One wave per
// 32-col group; 2 row-tile accumulators; B streams coalesced from packed
// chunks (lane*16B within 1KB chunk). A/B frag [idx=lane&31][k=(lane>>5)*8+j],
// C/D col=lane&31, row=(r&3)+8*(r>>2)+4*(lane>>5).
// MODE 0: +bias+cond*wcol; MODE 1: +bias, relu; MODE 2: +bias.
template<int KT, int NACT, int MODE, int LIMIT>
__device__ __forceinline__ void gemm32(
    const bf16* Asrc, int lda,
    const bf16* __restrict__ Wp,
    const float* __restrict__ bias, const float* __restrict__ wcol,
    const float* condl, bf16* dst, int ldd,
    int w, int lane, bool preEpiSync)
{
    const bool act  = (w < NACT);
    const int  l31  = lane & 31;
    const int  kh8  = (lane >> 5) * 8;
    const bf16* Bp  = Wp + ((size_t)w * KT) * 512 + lane * 8;
    const bf16* Ap  = Asrc + l31 * lda + kh8;

    f32x16 acc0 = {}, acc1 = {};
    constexpr int CH = (KT < 8) ? KT : 8;              // B-preload burst depth
    #pragma unroll
    for (int khb = 0; khb < KT / CH; ++khb) {
        bf16x8 bq[CH];
        if (act) {
            #pragma unroll
            for (int c = 0; c < CH; ++c)
                bq[c] = *reinterpret_cast<const bf16x8*>(Bp + (khb * CH + c) * 512);
            #pragma unroll
            for (int c = 0; c < CH; ++c) {
                int kt = khb * CH + c;
                bf16x8 a0 = *reinterpret_cast<const bf16x8*>(Ap + kt * 16);
                bf16x8 a1 = *reinterpret_cast<const bf16x8*>(Ap + 32 * lda + kt * 16);
                acc0 = __builtin_amdgcn_mfma_f32_32x32x16_bf16(a0, bq[c], acc0, 0, 0, 0);
                acc1 = __builtin_amdgcn_mfma_f32_32x32x16_bf16(a1, bq[c], acc1, 0, 0, 0);
            }
        }
    }

    if (preEpiSync) __syncthreads();   // in-place layers: all A reads done

    if (act) {
        const int col = w * 32 + l31;
        if (NACT == 8 || col < LIMIT) {
            const float bv  = bias[col];
            const float wcv = (MODE == 0) ? wcol[col] : 0.f;
            #pragma unroll
            for (int r = 0; r < 16; ++r) {
                int row = (r & 3) + 8 * (r >> 2) + (kh8 >> 1);  // +4*(lane>>5)
                float v0 = acc0[r] + bv;
                float v1 = acc1[r] + bv;
                if (MODE == 0) { v0 += condl[row] * wcv; v1 += condl[row + 32] * wcv; }
                if (MODE == 1) { v0 = fmaxf(v0, 0.f);   v1 = fmaxf(v1, 0.f); }
                dst[row * ldd + col]        = (bf16)v0;
                dst[(row + 32) * ldd + col] = (bf16)v1;
            }
        }
    }
    __syncthreads();
}

// RQ spline for NF features starting at fb; params in pbuf (stride 208).
template<int NF>
__device__ __forceinline__ void do_spline(int fb, float* zf, bf16* zb,
                                          const bf16* pbuf, float* ldl, int t)
{
    for (int task = t; task < 64 * NF; task += 512) {
        int r  = task / NF;
        int fl = task - r * NF;
        const bf16* pp = pbuf + r * 208 + fl * 23;
        float P[23];
        #pragma unroll
        for (int m = 0; m < 23; ++m) P[m] = (float)pp[m];

        float xin = zf[r * 46 + fb + fl];
        float xc  = fminf(fmaxf(xin, -TAILF), TAILF);
        bool inside = (xin >= -TAILF) && (xin <= TAILF);

        float mw = P[0];
        #pragma unroll
        for (int i = 1; i < 8; ++i) mw = fmaxf(mw, P[i]);
        float ew[8], sw = 0.f;
        #pragma unroll
        for (int i = 0; i < 8; ++i) { ew[i] = __expf((P[i] - mw) * 0.0625f); sw += ew[i]; }
        float rws = 0.992f / sw;
        float cw[9]; cw[0] = -TAILF;
        #pragma unroll
        for (int i = 0; i < 8; ++i)
            cw[i + 1] = cw[i] + 2.f * TAILF * (1e-3f + ew[i] * rws);
        cw[8] = TAILF;
        float wb[8];
        #pragma unroll
        for (int i = 0; i < 8; ++i) wb[i] = cw[i + 1] - cw[i];

        float mh = P[8];
        #pragma unroll
        for (int i = 1; i < 8; ++i) mh = fmaxf(mh, P[8 + i]);
        float eh[8], sh = 0.f;
        #pragma unroll
        for (int i = 0; i < 8; ++i) { eh[i] = __expf((P[8 + i] - mh) * 0.0625f); sh += eh[i]; }
        float rhs = 0.992f / sh;
        float ch[9]; ch[0] = -TAILF;
        #pragma unroll
        for (int i = 0; i < 8; ++i)
            ch[i + 1] = ch[i] + 2.f * TAILF * (1e-3f + eh[i] * rhs);
        ch[8] = TAILF;
        float hb[8];
        #pragma unroll
        for (int i = 0; i < 8; ++i) hb[i] = ch[i + 1] - ch[i];

        float dd[9];
        dd[0] = 1.0f; dd[8] = 1.0f;
        #pragma unroll
        for (int i = 1; i < 8; ++i)
            dd[i] = 1e-3f + __logf(1.f + __expf(P[15 + i]));

        float icw = cw[0], ich = ch[0], ibw = wb[0], ibh = hb[0];
        float id0 = dd[0], id1 = dd[1];
        #pragma unroll
        for (int i = 1; i < 8; ++i) {
            bool ge = xc >= cw[i];
            icw = ge ? cw[i] : icw;  ich = ge ? ch[i] : ich;
            ibw = ge ? wb[i] : ibw;  ibh = ge ? hb[i] : ibh;
            id0 = ge ? dd[i] : id0;  id1 = ge ? dd[i + 1] : id1;
        }

        float th  = (xc - icw) / ibw;
        float th1 = th * (1.f - th);
        float dl  = ibh / ibw;
        float den = dl + (id0 + id1 - 2.f * dl) * th1;
        float yy  = ich + ibh * (dl * th * th + id0 * th1) / den;
        float num = dl * dl * (id1 * th * th + 2.f * dl * th1
                               + id0 * (1.f - th) * (1.f - th));
        float lad = __logf(num) - 2.f * __logf(den);

        if (inside) {
            zf[r * 46 + fb + fl] = yy;
            zb[r * 72 + fb + fl] = (bf16)yy;
            atomicAdd(&ldl[r], lad);
        }
    }
}

__global__ __launch_bounds__(512, 4) void maf_main(
    const float* __restrict__ x, const float* __restrict__ cond,
    const float* __restrict__ bh_all,
    const bf16* __restrict__ W0m, const bf16* __restrict__ Whm,
    const bf16* __restrict__ Wfm,
    const float* __restrict__ beff, const float* __restrict__ bfp,
    const float* __restrict__ Wcc,
    float* __restrict__ out, int B)
{
    extern __shared__ char smem[];
    float* zf    = (float*)(smem + SO_ZF);
    bf16*  zb    = (bf16*)(smem + SO_ZB);
    bf16*  hidA  = (bf16*)(smem + SO_HIDA);
    bf16*  pbuf  = (bf16*)(smem + SO_PBUF);
    float* condl = (float*)(smem + SO_COND);
    float* ldl   = (float*)(smem + SO_LD);

    const int t    = threadIdx.x;
    const int r0   = blockIdx.x * 64;
    const int w    = t >> 6;
    const int lane = t & 63;

    for (int i = t; i < 64 * 27; i += 512) {
        int r = i / 27, c = i - (i / 27) * 27;
        zb[r * 72 + 45 + c] = (bf16)0.f;
    }
    for (int i = t; i < 64 * 45; i += 512) {
        int r = i / 45, f = i - (i / 45) * 45;
        float v = (r0 + r < B) ? x[(size_t)(r0 + r) * 45 + f] : 0.f;
        zf[r * 46 + f] = v;
        zb[r * 72 + f] = (bf16)v;
    }
    if (t < 64) {
        condl[t] = (r0 + t < B) ? cond[r0 + t] : 0.f;
        ldl[t]   = 0.f;
    }
    __syncthreads();

    #pragma unroll 1
    for (int b = 0; b < 6; ++b) {
        // input MADE layer: K=64 (padded from 45), +cond*Wc + (b0+bc)
        gemm32<4, 8, 0, 256>(zb, 72, W0m + b * 16384,
                             beff + b * 256, Wcc + b * 256, condl,
                             hidA, 264, w, lane, false);
        // 2 hidden layers, relu, in-place
        #pragma unroll 1
        for (int l = 0; l < 2; ++l)
            gemm32<16, 8, 1, 256>(hidA, 264, Whm + (b * 2 + l) * 65536,
                                  bh_all + (b * 2 + l) * 256, nullptr, condl,
                                  hidA, 264, w, lane, true);
        // params: 5 groups x 9 features (207 real cols of 224)
        #pragma unroll 1
        for (int g = 0; g < 5; ++g) {
            gemm32<16, 7, 2, 208>(hidA, 264, Wfm + (size_t)(b * 5 + g) * 57344,
                                  bfp + (b * 5 + g) * 224, nullptr, condl,
                                  pbuf, 208, w, lane, false);
            do_spline<9>(g * 9, zf, zb, pbuf, ldl, t);
            __syncthreads();
        }
    }

    if (t < 64 && r0 + t < B) {
        float s = 0.f;
        #pragma unroll
        for (int f = 0; f < 45; ++f) { float v = zf[t * 46 + f]; s += v * v; }
        out[r0 + t] = -0.5f * s - LOGZ + ldl[t];
    }
}

// ---------------- host entry ----------------
extern "C" void kernel_launch(void* const* d_in, const int* in_sizes, int n_in,
                              void* d_out, int out_size, void* d_ws, size_t ws_size,
                              hipStream_t stream)
{
    const float* x    = (const float*)d_in[0];
    const float* cond = (const float*)d_in[1];
    const float* W0   = (const float*)d_in[2];
    const float* b0   = (const float*)d_in[3];
    const float* Wc   = (const float*)d_in[4];
    const float* bc   = (const float*)d_in[5];
    const float* Wh   = (const float*)d_in[6];
    const float* bh   = (const float*)d_in[7];
    const float* Wf   = (const float*)d_in[8];
    const float* bfv  = (const float*)d_in[9];
    float* out = (float*)d_out;

    const int B = in_sizes[0] / 45;
    if (ws_size < (size_t)WS_NEED) return;   // fail loudly

    char* ws = (char*)d_ws;
    bf16*  W0m  = (bf16*)(ws + WS_W0M);
    bf16*  Whm  = (bf16*)(ws + WS_WHM);
    bf16*  Wfm  = (bf16*)(ws + WS_WFM);
    float* beff = (float*)(ws + WS_BEFF);
    float* bfp  = (float*)(ws + WS_BFP);
    float* Wcc  = (float*)(ws + WS_WCC);

    prep_all<<<(N_PREP + 255) / 256, 256, 0, stream>>>(
        W0, b0, Wc, bc, Wh, Wf, bfv, W0m, Whm, Wfm, beff, bfp, Wcc);

    (void)hipFuncSetAttribute((const void*)maf_main,
                              hipFuncAttributeMaxDynamicSharedMemorySize,
                              SMEM_BYTES);

    const int nwg = (B + 63) / 64;
    maf_main<<<nwg, 512, SMEM_BYTES, stream>>>(
        x, cond, bh, W0m, Whm, Wfm, beff, bfp, Wcc, out, B);
}